// Round 1
// 233.029 us; speedup vs baseline: 1.0880x; 1.0880x over previous
//
#include <hip/hip_runtime.h>
#include <math.h>

#define T_TOTAL 16384
#define HDIM    2048
#define NEXP    64

// ---------------------------------------------------------------------------
// LDS-tiled register GEMM with global->register prefetch double-buffering.
//   partial[t][ks][e] = sum_{k in slice ks} x[t][k] * w[e][k]
// Block: 256 threads, 256 tokens x 64 experts; thread: 8x8 acc tile.
// KS=8  -> grid 512 (2 blocks/CU); BK=32 -> LDS 41.5 KB; 4096 VALU-cy of FMA
// per barrier pair hides the ~900 cy HBM latency of the next tile's loads,
// which are issued into registers immediately after the post-store barrier.
// Strides 258/66 (== 2 mod 32): transpose staging writes are exactly 2-way
// bank-aliased = free (m136); inner reads are 2-way = free.
// ---------------------------------------------------------------------------
template<int KS>
__global__ __launch_bounds__(256, 2)
void router_gemm_kernel(const float* __restrict__ x,
                        const float* __restrict__ w,
                        float* __restrict__ partial)
{
    constexpr int KSLICE = HDIM / KS;   // 256 for KS=8
    constexpr int BK     = 32;
    constexpr int XS_ST  = 258;         // 256 tokens + 2 pad
    constexpr int WS_ST  = 66;          // 64 experts + 2 pad

    __shared__ float Xs[BK][XS_ST];     // [k][token]
    __shared__ float Ws[BK][WS_ST];     // [k][expert]

    const int tid = threadIdx.x;
    const int tb  = blockIdx.x & 63;    // token block (64 x 256 tokens)
    const int ks  = blockIdx.x >> 6;    // k-slice
    const int t0  = tb * 256;
    const int k0  = ks * KSLICE;

    const int kq  = tid & 3;            // staging k-chunk (kq*8 .. +7)
    const int rr  = tid >> 2;           // staging row 0..63

    const int eg8 = (tid & 7) * 8;      // this thread's 8 experts
    const int tg8 = (tid >> 3) * 8;     // this thread's 8 tokens

    float acc[8][8];
#pragma unroll
    for (int i = 0; i < 8; ++i)
#pragma unroll
        for (int j = 0; j < 8; ++j) acc[i][j] = 0.0f;

    const float* xg = x + (size_t)t0 * HDIM + k0 + kq * 8;
    const float* wg = w + (size_t)rr * HDIM + k0 + kq * 8;

    float4 px[4][2];                    // 4 tokens x 8 k-floats
    float4 pw[2];                       // 1 expert  x 8 k-floats

    // prologue: prefetch tile 0 into registers
#pragma unroll
    for (int p = 0; p < 4; ++p) {
        const float* src = xg + (size_t)(p * 64 + rr) * HDIM;
        px[p][0] = *(const float4*)(src);
        px[p][1] = *(const float4*)(src + 4);
    }
    pw[0] = *(const float4*)(wg);
    pw[1] = *(const float4*)(wg + 4);

#pragma unroll 1
    for (int kc = 0; kc < KSLICE; kc += BK) {
        __syncthreads();                // previous tile's LDS reads done

        // store prefetched tile, transposed -> [k][token] / [k][expert]
#pragma unroll
        for (int p = 0; p < 4; ++p) {
            const int r = p * 64 + rr;
            Xs[kq * 8 + 0][r] = px[p][0].x;
            Xs[kq * 8 + 1][r] = px[p][0].y;
            Xs[kq * 8 + 2][r] = px[p][0].z;
            Xs[kq * 8 + 3][r] = px[p][0].w;
            Xs[kq * 8 + 4][r] = px[p][1].x;
            Xs[kq * 8 + 5][r] = px[p][1].y;
            Xs[kq * 8 + 6][r] = px[p][1].z;
            Xs[kq * 8 + 7][r] = px[p][1].w;
        }
        Ws[kq * 8 + 0][rr] = pw[0].x;
        Ws[kq * 8 + 1][rr] = pw[0].y;
        Ws[kq * 8 + 2][rr] = pw[0].z;
        Ws[kq * 8 + 3][rr] = pw[0].w;
        Ws[kq * 8 + 4][rr] = pw[1].x;
        Ws[kq * 8 + 5][rr] = pw[1].y;
        Ws[kq * 8 + 6][rr] = pw[1].z;
        Ws[kq * 8 + 7][rr] = pw[1].w;

        __syncthreads();                // tile visible to all waves

        // issue next tile's loads NOW; latency hides under the 32-k compute
        if (kc + BK < KSLICE) {
            const float* xn = xg + (kc + BK);
#pragma unroll
            for (int p = 0; p < 4; ++p) {
                const float* src = xn + (size_t)(p * 64 + rr) * HDIM;
                px[p][0] = *(const float4*)(src);
                px[p][1] = *(const float4*)(src + 4);
            }
            pw[0] = *(const float4*)(wg + kc + BK);
            pw[1] = *(const float4*)(wg + kc + BK + 4);
        }

#pragma unroll 8
        for (int k = 0; k < BK; ++k) {
            float xv[8], wv[8];
#pragma unroll
            for (int i = 0; i < 8; ++i) xv[i] = Xs[k][tg8 + i];
#pragma unroll
            for (int j = 0; j < 8; ++j) wv[j] = Ws[k][eg8 + j];
#pragma unroll
            for (int i = 0; i < 8; ++i)
#pragma unroll
                for (int j = 0; j < 8; ++j)
                    acc[i][j] = fmaf(xv[i], wv[j], acc[i][j]);
        }
    }

    // write partial [t][ks][e] -> top-k reads each token contiguously
    float* pp = partial + ((size_t)(t0 + tg8) * KS + ks) * NEXP + eg8;
#pragma unroll
    for (int i = 0; i < 8; ++i) {
        float* q = pp + (size_t)i * KS * NEXP;
        *(float4*)(q)     = make_float4(acc[i][0], acc[i][1], acc[i][2], acc[i][3]);
        *(float4*)(q + 4) = make_float4(acc[i][4], acc[i][5], acc[i][6], acc[i][7]);
    }
}

// ---------------------------------------------------------------------------
// Sum KS partials + sigmoid + biased top-8 (desc, ties -> lower idx) +
// renorm * 2.5. One wave per token, lane = expert. KS templated so the
// reduction loop fully unrolls -> 8 independent loads in flight per wave.
// ---------------------------------------------------------------------------
template<int KS>
__global__ __launch_bounds__(256)
void router_topk_kernel(const float* __restrict__ partial,
                        const float* __restrict__ bias,
                        float* __restrict__ out_scores,
                        float* __restrict__ out_idx)
{
    const int token = blockIdx.x * 4 + (threadIdx.x >> 6);
    const int lane  = threadIdx.x & 63;

    const float* pt = partial + (size_t)token * KS * NEXP + lane;
    float logit = 0.0f;
#pragma unroll
    for (int s = 0; s < KS; ++s) logit += pt[(size_t)s * NEXP];

    const float score = 1.0f / (1.0f + expf(-logit));
    float key = score + bias[lane];

    float myscore = 0.0f;
    int   myidx   = 0;
    float denom   = 0.0f;

#pragma unroll
    for (int r = 0; r < 8; ++r) {
        float bk = key;
        int   bi = lane;
#pragma unroll
        for (int off = 32; off > 0; off >>= 1) {
            const float ok = __shfl_xor(bk, off);
            const int   oi = __shfl_xor(bi, off);
            if (ok > bk || (ok == bk && oi < bi)) { bk = ok; bi = oi; }
        }
        const float wsc = __shfl(score, bi);   // raw (unbiased) winner score
        denom += wsc;
        if (lane == r)  { myscore = wsc; myidx = bi; }
        if (lane == bi) key = -__builtin_inff();
    }

    const float factor = 2.5f / (denom + 1e-20f);
    if (lane < 8) {
        out_scores[(size_t)token * 8 + lane] = myscore * factor;
        out_idx  [(size_t)token * 8 + lane] = (float)myidx;
    }
}

// ---------------------------------------------------------------------------
extern "C" void kernel_launch(void* const* d_in, const int* in_sizes, int n_in,
                              void* d_out, int out_size, void* d_ws, size_t ws_size,
                              hipStream_t stream)
{
    const float* x    = (const float*)d_in[0];   // [4,4096,2048] f32
    const float* bias = (const float*)d_in[1];   // [64] f32
    const float* w    = (const float*)d_in[2];   // [64,2048] f32

    float* out     = (float*)d_out;
    float* partial = (float*)d_ws;

    const size_t bytesPerSlice = (size_t)T_TOTAL * NEXP * 4;   // 4 MiB

    if (ws_size >= 8 * bytesPerSlice) {          // 32 MiB (64 MiB confirmed avail)
        router_gemm_kernel<8><<<dim3(64 * 8), dim3(256), 0, stream>>>(x, w, partial);
        router_topk_kernel<8><<<dim3(T_TOTAL / 4), dim3(256), 0, stream>>>(
            partial, bias, out, out + (size_t)T_TOTAL * 8);
    } else {                                     // safety fallback
        router_gemm_kernel<4><<<dim3(64 * 4), dim3(256), 0, stream>>>(x, w, partial);
        router_topk_kernel<4><<<dim3(T_TOTAL / 4), dim3(256), 0, stream>>>(
            partial, bias, out, out + (size_t)T_TOTAL * 8);
    }
}